// Round 9
// baseline (89.053 us; speedup 1.0000x reference)
//
#include <hip/hip_runtime.h>

// Problem constants (fixed by setup_inputs)
constexpr int NB  = 4;     // batch
constexpr int NPT = 2048;  // points (N)
constexpr int KNN = 32;    // neighbors (K)
constexpr int CIN = 6;     // in_channels
constexpr int CF  = 64;    // feat channels
constexpr int CO  = 64;    // out channels
constexpr float EPS = 1e-5f;

typedef short bf16x8 __attribute__((ext_vector_type(8)));   // 8 bf16 in 4 VGPRs
typedef float f32x4  __attribute__((ext_vector_type(4)));

// ---------------- workspace layout (bytes) ----------------
constexpr size_t WS_WA  = 0;       // WAf bf16[6*4*2*64*8] (sa-folded, row-permuted)
constexpr size_t WS_WL  = 49152;   // WLf bf16[4*2*64*8]  (sl-folded)
constexpr size_t WS_WR  = 57344;   // WRf bf16[4*2*64*8]  (sr-folded)
constexpr size_t WS_BA  = 65536;   // baP f32[6*64]
constexpr size_t WS_BNF = 67072;   // bnf f32[3*64]  (s1, b1, blr)

__device__ __host__ inline unsigned short bf16_rne(float f) {
  unsigned u = __builtin_bit_cast(unsigned, f);
  u += 0x7fffu + ((u >> 16) & 1u);
  return (unsigned short)(u >> 16);
}

__global__ void setup_kernel(const float *Wattn, const float *Wlin, const float *Wres,
                             const float *ga, const float *ba, const float *ma, const float *va,
                             const float *g1, const float *b1, const float *m1, const float *v1,
                             const float *gl, const float *bl, const float *ml, const float *vl,
                             const float *gr, const float *br, const float *mr, const float *vr,
                             unsigned short *WAf, unsigned short *WLf, unsigned short *WRf,
                             float *baP, float *bnf) {
  const int t = blockIdx.x * blockDim.x + threadIdx.x;
  const int stride = gridDim.x * blockDim.x;
  for (int e = t; e < 6 * 4 * 2 * 64 * 8; e += stride) {
    const int j = e & 7, l = (e >> 3) & 63, ks = (e >> 9) & 1, ot = (e >> 10) & 3, i = e >> 12;
    const int m = l & 15, cg = l >> 4;
    const int cc = ks * 32 + cg * 8 + j;
    const int row = (ot * 16 + m) * CIN + i;
    const float sa = ga[row] * rsqrtf(va[row] + EPS);
    WAf[e] = bf16_rne(Wattn[row * CF + cc] * sa);
  }
  for (int e = t; e < 4 * 2 * 64 * 8; e += stride) {
    const int j = e & 7, l = (e >> 3) & 63, ks = (e >> 9) & 1, ot = e >> 10;
    const int m = l & 15;
    const int cc = ks * 32 + (l >> 4) * 8 + j;
    const int row = ot * 16 + m;
    const float sl = gl[row] * rsqrtf(vl[row] + EPS);
    const float sr = gr[row] * rsqrtf(vr[row] + EPS);
    WLf[e] = bf16_rne(Wlin[row * CF + cc] * sl);
    WRf[e] = bf16_rne(Wres[row * CF + cc] * sr);
  }
  for (int e = t; e < 384; e += stride) {
    const int i = e >> 6, o = e & 63;
    const int j0 = o * CIN + i;
    const float sa = ga[j0] * rsqrtf(va[j0] + EPS);
    baP[e] = ba[j0] - ma[j0] * sa;
  }
  for (int e = t; e < 64; e += stride) {
    const float s1v = g1[e] * rsqrtf(v1[e] + EPS);
    bnf[e]      = s1v;
    bnf[64 + e] = b1[e] - m1[e] * s1v;
    const float slv = gl[e] * rsqrtf(vl[e] + EPS);
    const float srv = gr[e] * rsqrtf(vr[e] + EPS);
    bnf[128 + e] = (bl[e] - ml[e] * slv) + (br[e] - mr[e] * srv);
  }
}

struct Params {
  const float *x, *y, *points, *feat;
  const float *Wq, *Wpos1, *Wpos2;
  const float *gq, *bq, *mq, *vq;
  const float *gp, *bp, *mp, *vp;
  const unsigned short *WAf, *WLf, *WRf;
  const float *baP, *bnf;
  float *out;
};

// TWO waves per point: wave handles output-column half ntw (16 of 32 k's).
// Per-wave private 2KB bf16 buffer recycled y -> P(unnorm exp) -> h.
// Only cross-wave dependency: softmax max & sum, exchanged via LDS with two
// block barriers. All fragment reads (Ba/By/Bh) are columns the wave itself
// wrote (B-rows = channels = own 64 lanes) -> in-wave DS FIFO ordering.
__global__ __launch_bounds__(256) void fused_pt_attn(Params p) {
  const int tid  = threadIdx.x;
  const int lane = tid & 63;
  const int wid  = tid >> 6;   // 0..3
  const int ptl  = wid >> 1;   // point within block (0/1)
  const int ntw  = wid & 1;    // column-half this wave owns
  // XCD-aware swizzle over 4096 blocks (8 XCDs x 512 contiguous).
  const int bid  = ((blockIdx.x & 7) << 9) | (blockIdx.x >> 3);
  const int pidx = bid * 2 + ptl;
  const int b    = pidx >> 11;
  const int n    = pidx & (NPT - 1);

  __shared__ unsigned short s_B[4][1024];  // per-wave 2KB frag buffer [k16][64]
  __shared__ float s_d[4][96];             // per-wave d[i][k16]
  __shared__ float s_f[4][32];             // per-wave feat
  __shared__ float s_mx[2][2][64];         // softmax half-max exchange
  __shared__ float s_sm[2][2][64];         // softmax half-sum exchange
  unsigned short *BB = s_B[wid];
  float *dW = s_d[wid];
  float *fW = s_f[wid];

  // ---- global stage (own column half) ----
  float ftv = 0.f, ptv = 0.f;
  if (lane < 32) ftv = p.feat[((size_t)b * 32 + lane) * NPT + n];
  if (lane < 3)  ptv = p.points[((size_t)b * 3 + lane) * NPT + n];
  const int xi = lane >> 3, xkl = (lane & 7) * 2;
  float2 x2 = make_float2(0.f, 0.f);
  if (lane < 48)
    x2 = *(const float2 *)(p.x + (((size_t)b * CIN + xi) * NPT + n) * KNN +
                           ntw * 16 + xkl);
  const float *w2p = p.Wpos2 + lane * 6;   // Wpos2[c][i]
  const float2 w2a = *(const float2 *)(w2p);
  const float2 w2b = *(const float2 *)(w2p + 2);
  const float2 w2c = *(const float2 *)(w2p + 4);
  const float w2[6] = {w2a.x, w2a.y, w2b.x, w2b.y, w2c.x, w2c.y};

  if (lane < 32) fW[lane] = ftv;

  // ---- pos1 (duplicated per wave; cheap) ----
  const float pt0 = __shfl(ptv, 0), pt1 = __shfl(ptv, 1), pt2 = __shfl(ptv, 2);
  float pos1[6];
#pragma unroll
  for (int i = 0; i < 6; ++i) {
    const float a = p.Wpos1[i * 3 + 0] * pt0 + p.Wpos1[i * 3 + 1] * pt1 +
                    p.Wpos1[i * 3 + 2] * pt2;
    const float s = p.gp[i] * rsqrtf(p.vp[i] + EPS);
    const float v = fmaf(a, s, p.bp[i] - p.mp[i] * s);
    pos1[i] = v > 0.f ? v : 0.2f * v;
  }

  // ---- d[i][k16] = pos1[i] - x (own half) ----
  if (lane < 48) {
    float pi = pos1[0];
    pi = (xi == 1) ? pos1[1] : pi;
    pi = (xi == 2) ? pos1[2] : pi;
    pi = (xi == 3) ? pos1[3] : pi;
    pi = (xi == 4) ? pos1[4] : pi;
    pi = (xi == 5) ? pos1[5] : pi;
    *(float2 *)(dW + xi * 16 + xkl) = make_float2(pi - x2.x, pi - x2.y);
  }

  // ---- x_q[lane] (duplicated per wave) ----
  float xq;
  {
    float acc = 0.f;
    const float *wq = p.Wq + lane * 32;
#pragma unroll
    for (int q = 0; q < 8; ++q) {
      const float4 w4 = *(const float4 *)(wq + q * 4);
      const float4 f4 = *(const float4 *)(fW + q * 4);
      acc = fmaf(w4.x, f4.x, fmaf(w4.y, f4.y, fmaf(w4.z, f4.z, fmaf(w4.w, f4.w, acc))));
    }
    const float s = p.gq[lane] * rsqrtf(p.vq[lane] + EPS);
    const float v = fmaf(acc, s, p.bq[lane] - p.mq[lane] * s);
    xq = v > 0.f ? v : 0.2f * v;
  }

  // ---- pre[k16] = sum_i w2[i]*d[i][k] ----
  float pre[16];
#pragma unroll
  for (int k = 0; k < 16; ++k) pre[k] = 0.f;
#pragma unroll
  for (int i = 0; i < 6; ++i) {
    const float wv = w2[i];
#pragma unroll
    for (int q = 0; q < 4; ++q) {
      const float4 d4 = *(const float4 *)(dW + i * 16 + q * 4);
      pre[q * 4 + 0] = fmaf(wv, d4.x, pre[q * 4 + 0]);
      pre[q * 4 + 1] = fmaf(wv, d4.y, pre[q * 4 + 1]);
      pre[q * 4 + 2] = fmaf(wv, d4.z, pre[q * 4 + 2]);
      pre[q * 4 + 3] = fmaf(wv, d4.w, pre[q * 4 + 3]);
    }
  }

  // ---- stream y (own half): stash bf16 frags, finalize pre ----
  const float *yrow = p.y + (((size_t)b * CF + lane) * NPT + n) * KNN + ntw * 16;
#pragma unroll
  for (int q = 0; q < 4; ++q) {
    const float4 y4 = *(const float4 *)(yrow + q * 4);
    const float yv[4] = {y4.x, y4.y, y4.z, y4.w};
#pragma unroll
    for (int j = 0; j < 4; ++j) {
      const int k = q * 4 + j;
      BB[k * 64 + (lane ^ ((k & 7) << 3))] = bf16_rne(yv[j]);
      pre[k] = (xq - yv[j] + pre[k]) * 0.125f;
    }
  }

  const int og = lane >> 4, kl = lane & 15;
  const int swz = (kl & 7) << 3;

  // ---- hoist y B-fragments (before P overwrites; in-wave order) ----
  bf16x8 By[2];
#pragma unroll
  for (int ks = 0; ks < 2; ++ks)
    By[ks] = *(const bf16x8 *)(BB + kl * 64 + ((ks * 32 + og * 8) ^ swz));

  // ---- softmax: half-max exchange, unnormalized exp over y, half-sum exch ----
  float mx = pre[0];
#pragma unroll
  for (int k = 1; k < 16; ++k) mx = fmaxf(mx, pre[k]);
  s_mx[ptl][ntw][lane] = mx;
  __syncthreads();
  mx = fmaxf(mx, s_mx[ptl][ntw ^ 1][lane]);

  float sum = 0.f;
#pragma unroll
  for (int k = 0; k < 16; ++k) {
    pre[k] = __expf(pre[k] - mx);
    BB[k * 64 + (lane ^ ((k & 7) << 3))] = bf16_rne(pre[k]);
    sum += pre[k];
  }
  s_sm[ptl][ntw][lane] = sum;

  // Ba hoist (own writes; no barrier needed for these)
  bf16x8 Ba[2];
#pragma unroll
  for (int ks = 0; ks < 2; ++ks)
    Ba[ks] = *(const bf16x8 *)(BB + kl * 64 + ((ks * 32 + og * 8) ^ swz));

  __syncthreads();
  sum += s_sm[ptl][ntw ^ 1][lane];
  const float inv = 1.f / sum;

  // ---- x values for the combine (own column kl) ----
  float xvv[6];
#pragma unroll
  for (int i = 0; i < 6; ++i) xvv[i] = pos1[i] - dW[i * 16 + kl];

  // ---- GEMM1 per o-tile: (g*inv + ba)*x combine, BN1+lrelu, h over P ----
  const bf16x8 *WAv = (const bf16x8 *)p.WAf;
#pragma unroll
  for (int ot = 0; ot < 4; ++ot) {
    f32x4 o0 = {0.f, 0.f, 0.f, 0.f};
#pragma unroll
    for (int i = 0; i < 6; ++i) {
      const bf16x8 A0 = WAv[((i * 4 + ot) * 2 + 0) * 64 + lane];
      const bf16x8 A1 = WAv[((i * 4 + ot) * 2 + 1) * 64 + lane];
      const f32x4 ba4 = *(const f32x4 *)(p.baP + i * 64 + ot * 16 + og * 4);
      f32x4 g = {0.f, 0.f, 0.f, 0.f};
      g = __builtin_amdgcn_mfma_f32_16x16x32_bf16(A0, Ba[0], g, 0, 0, 0);
      g = __builtin_amdgcn_mfma_f32_16x16x32_bf16(A1, Ba[1], g, 0, 0, 0);
      const float xv = xvv[i];
#pragma unroll
      for (int r = 0; r < 4; ++r)
        o0[r] = fmaf(fmaf(g[r], inv, ba4[r]), xv, o0[r]);
    }
    const f32x4 s14 = *(const f32x4 *)(p.bnf + 0 * 64 + ot * 16 + og * 4);
    const f32x4 b14 = *(const f32x4 *)(p.bnf + 1 * 64 + ot * 16 + og * 4);
    unsigned hp[4];
#pragma unroll
    for (int r = 0; r < 4; ++r) {
      const float t = fmaf(s14[r], o0[r], b14[r]);
      hp[r] = bf16_rne(t > 0.f ? t : 0.2f * t);
    }
    const int idx = kl * 64 + ((ot * 16 + og * 4) ^ swz);
    *(uint2 *)(BB + idx) = make_uint2(hp[0] | (hp[1] << 16), hp[2] | (hp[3] << 16));
  }

  // ---- GEMM2: out = lrelu( Wlin'@h + Wres'@y + blr ) ----
  bf16x8 Bh[2];
#pragma unroll
  for (int ks = 0; ks < 2; ++ks)
    Bh[ks] = *(const bf16x8 *)(BB + kl * 64 + ((ks * 32 + og * 8) ^ swz));

  const bf16x8 *WLv = (const bf16x8 *)p.WLf;
  const bf16x8 *WRv = (const bf16x8 *)p.WRf;
#pragma unroll
  for (int ot = 0; ot < 4; ++ot) {
    const bf16x8 L0 = WLv[(ot * 2 + 0) * 64 + lane];
    const bf16x8 L1 = WLv[(ot * 2 + 1) * 64 + lane];
    const bf16x8 R0 = WRv[(ot * 2 + 0) * 64 + lane];
    const bf16x8 R1 = WRv[(ot * 2 + 1) * 64 + lane];
    const f32x4 blr = *(const f32x4 *)(p.bnf + 2 * 64 + ot * 16 + og * 4);
    f32x4 a = {0.f, 0.f, 0.f, 0.f};
    a = __builtin_amdgcn_mfma_f32_16x16x32_bf16(L0, Bh[0], a, 0, 0, 0);
    a = __builtin_amdgcn_mfma_f32_16x16x32_bf16(L1, Bh[1], a, 0, 0, 0);
    a = __builtin_amdgcn_mfma_f32_16x16x32_bf16(R0, By[0], a, 0, 0, 0);
    a = __builtin_amdgcn_mfma_f32_16x16x32_bf16(R1, By[1], a, 0, 0, 0);
    float *ob = p.out + (((size_t)(b * CO + ot * 16 + og * 4)) * NPT + n) * KNN +
                kl + ntw * 16;
#pragma unroll
    for (int r = 0; r < 4; ++r) {
      const float v = a[r] + blr[r];
      ob[(size_t)r * NPT * KNN] = v > 0.f ? v : 0.2f * v;
    }
  }
}

extern "C" void kernel_launch(void *const *d_in, const int *in_sizes, int n_in,
                              void *d_out, int out_size, void *d_ws, size_t ws_size,
                              hipStream_t stream) {
  char *ws = (char *)d_ws;
  unsigned short *WAf = (unsigned short *)(ws + WS_WA);
  unsigned short *WLf = (unsigned short *)(ws + WS_WL);
  unsigned short *WRf = (unsigned short *)(ws + WS_WR);
  float *baP = (float *)(ws + WS_BA);
  float *bnf = (float *)(ws + WS_BNF);

  setup_kernel<<<dim3(96), dim3(256), 0, stream>>>(
      (const float *)d_in[7], (const float *)d_in[8], (const float *)d_in[9],
      (const float *)d_in[18], (const float *)d_in[19], (const float *)d_in[20], (const float *)d_in[21],
      (const float *)d_in[22], (const float *)d_in[23], (const float *)d_in[24], (const float *)d_in[25],
      (const float *)d_in[26], (const float *)d_in[27], (const float *)d_in[28], (const float *)d_in[29],
      (const float *)d_in[30], (const float *)d_in[31], (const float *)d_in[32], (const float *)d_in[33],
      WAf, WLf, WRf, baP, bnf);

  Params p;
  p.x      = (const float *)d_in[0];
  p.y      = (const float *)d_in[1];
  p.points = (const float *)d_in[2];
  p.feat   = (const float *)d_in[3];
  p.Wq     = (const float *)d_in[4];
  p.Wpos1  = (const float *)d_in[5];
  p.Wpos2  = (const float *)d_in[6];
  p.gq = (const float *)d_in[10]; p.bq = (const float *)d_in[11];
  p.mq = (const float *)d_in[12]; p.vq = (const float *)d_in[13];
  p.gp = (const float *)d_in[14]; p.bp = (const float *)d_in[15];
  p.mp = (const float *)d_in[16]; p.vp = (const float *)d_in[17];
  p.WAf = WAf; p.WLf = WLf; p.WRf = WRf;
  p.baP = baP; p.bnf = bnf;
  p.out = (float *)d_out;

  fused_pt_attn<<<dim3(NB * NPT / 2), dim3(256), 0, stream>>>(p);
}

// Round 10
// 79.499 us; speedup vs baseline: 1.1202x; 1.1202x over previous
//
#include <hip/hip_runtime.h>
#include <hip/hip_bf16.h>

// Problem constants (fixed by setup_inputs)
constexpr int NB  = 4;     // batch
constexpr int NPT = 2048;  // points (N)
constexpr int KNN = 32;    // neighbors (K)
constexpr int CIN = 6;     // in_channels
constexpr int CF  = 64;    // feat channels
constexpr int CO  = 64;    // out channels
constexpr float EPS = 1e-5f;
constexpr float S2  = 0.125f * 1.44269504f;  // (1/sqrt(Cf)) * log2(e)

typedef short bf16x8 __attribute__((ext_vector_type(8)));   // 8 bf16 in 4 VGPRs
typedef float f32x4  __attribute__((ext_vector_type(4)));

// ---------------- workspace layout (bytes) ----------------
constexpr size_t WS_WA  = 0;       // WAf bf16[6*4*2*64*8] (sa-folded, row-permuted)
constexpr size_t WS_WL  = 49152;   // WLf bf16[4*2*64*8]  (sl-folded)
constexpr size_t WS_WR  = 57344;   // WRf bf16[4*2*64*8]  (sr-folded)
constexpr size_t WS_BA  = 65536;   // baP f32[6*64]
constexpr size_t WS_BNF = 67072;   // bnf f32[3*64]  (s1, b1, blr)

__device__ __host__ inline unsigned short bf16_rne(float f) {
  unsigned u = __builtin_bit_cast(unsigned, f);
  u += 0x7fffu + ((u >> 16) & 1u);
  return (unsigned short)(u >> 16);
}

// packed RNE f32x2 -> bf16x2; low short = a
__device__ inline unsigned pk2(float a, float b) {
  __hip_bfloat162 h = __float22bfloat162_rn(float2{a, b});
  unsigned u;
  __builtin_memcpy(&u, &h, 4);
  return u;
}

__global__ void setup_kernel(const float *Wattn, const float *Wlin, const float *Wres,
                             const float *ga, const float *ba, const float *ma, const float *va,
                             const float *g1, const float *b1, const float *m1, const float *v1,
                             const float *gl, const float *bl, const float *ml, const float *vl,
                             const float *gr, const float *br, const float *mr, const float *vr,
                             unsigned short *WAf, unsigned short *WLf, unsigned short *WRf,
                             float *baP, float *bnf) {
  const int t = blockIdx.x * blockDim.x + threadIdx.x;
  const int stride = gridDim.x * blockDim.x;
  for (int e = t; e < 6 * 4 * 2 * 64 * 8; e += stride) {
    const int j = e & 7, l = (e >> 3) & 63, ks = (e >> 9) & 1, ot = (e >> 10) & 3, i = e >> 12;
    const int m = l & 15, cg = l >> 4;
    const int cc = ks * 32 + cg * 8 + j;
    const int row = (ot * 16 + m) * CIN + i;
    const float sa = ga[row] * rsqrtf(va[row] + EPS);
    WAf[e] = bf16_rne(Wattn[row * CF + cc] * sa);
  }
  for (int e = t; e < 4 * 2 * 64 * 8; e += stride) {
    const int j = e & 7, l = (e >> 3) & 63, ks = (e >> 9) & 1, ot = e >> 10;
    const int m = l & 15;
    const int cc = ks * 32 + (l >> 4) * 8 + j;
    const int row = ot * 16 + m;
    const float sl = gl[row] * rsqrtf(vl[row] + EPS);
    const float sr = gr[row] * rsqrtf(vr[row] + EPS);
    WLf[e] = bf16_rne(Wlin[row * CF + cc] * sl);
    WRf[e] = bf16_rne(Wres[row * CF + cc] * sr);
  }
  for (int e = t; e < 384; e += stride) {
    const int i = e >> 6, o = e & 63;
    const int j0 = o * CIN + i;
    const float sa = ga[j0] * rsqrtf(va[j0] + EPS);
    baP[e] = ba[j0] - ma[j0] * sa;
  }
  for (int e = t; e < 64; e += stride) {
    const float s1v = g1[e] * rsqrtf(v1[e] + EPS);
    bnf[e]      = s1v;
    bnf[64 + e] = b1[e] - m1[e] * s1v;
    const float slv = gl[e] * rsqrtf(vl[e] + EPS);
    const float srv = gr[e] * rsqrtf(vr[e] + EPS);
    bnf[128 + e] = (bl[e] - ml[e] * slv) + (br[e] - mr[e] * srv);
  }
}

struct Params {
  const float *x, *y, *points, *feat;
  const float *Wq, *Wpos1, *Wpos2;
  const float *gq, *bq, *mq, *vq;
  const float *gp, *bp, *mp, *vp;
  const unsigned short *WAf, *WLf, *WRf;
  const float *baP, *bnf;
  float *out;
};

// One wave per point; no block barriers. Separate per-wave y and P/h bf16
// frag buffers (R3 structure, best measured). x is never staged in LDS:
// pre-term reads x via wave-uniform broadcast float4 global loads (L1),
// GEMM1 combine reads x via 12 scalar global loads. Unnormalized P with
// 1/sum folded as out = sum(g*(inv*x)) + sum(ba*x); exp2-domain softmax.
__global__ __launch_bounds__(256) void fused_pt_attn(Params p) {
  const int tid  = threadIdx.x;
  const int lane = tid & 63;
  const int wid  = tid >> 6;
  // XCD-aware swizzle: 2048 blocks, 8 XCDs -> each XCD gets a contiguous range.
  const int bid  = ((blockIdx.x & 7) << 8) + (blockIdx.x >> 3);
  const int pidx = bid * 4 + wid;
  const int b    = pidx >> 11;
  const int n    = pidx & (NPT - 1);

  __shared__ unsigned short s_Y[4][2048];   // y bf16 frags per wave
  __shared__ unsigned short s_P[4][2048];   // P (unnorm exp) -> h per wave
  __shared__ float s_f[4][32];              // feat per wave
  unsigned short *YB = s_Y[wid];
  unsigned short *PB = s_P[wid];
  float *fW = s_f[wid];

  // ---- stage small inputs ----
  float ftv = 0.f, ptv = 0.f;
  if (lane < 32) ftv = p.feat[((size_t)b * 32 + lane) * NPT + n];
  if (lane < 3)  ptv = p.points[((size_t)b * 3 + lane) * NPT + n];
  const float *w2p = p.Wpos2 + lane * 6;   // Wpos2[c][i], row per lane channel
  const float2 w2a = *(const float2 *)(w2p);
  const float2 w2b = *(const float2 *)(w2p + 2);
  const float2 w2c = *(const float2 *)(w2p + 4);
  const float w2[6] = {w2a.x, w2a.y, w2b.x, w2b.y, w2c.x, w2c.y};

  if (lane < 32) fW[lane] = ftv;

  // ---- pos1 (all lanes) ----
  const float pt0 = __shfl(ptv, 0), pt1 = __shfl(ptv, 1), pt2 = __shfl(ptv, 2);
  float pos1[6];
#pragma unroll
  for (int i = 0; i < 6; ++i) {
    const float a = p.Wpos1[i * 3 + 0] * pt0 + p.Wpos1[i * 3 + 1] * pt1 +
                    p.Wpos1[i * 3 + 2] * pt2;
    const float s = p.gp[i] * rsqrtf(p.vp[i] + EPS);
    const float v = fmaf(a, s, p.bp[i] - p.mp[i] * s);
    pos1[i] = v > 0.f ? v : 0.2f * v;
  }

  // ---- x_q[lane] (fW written by this wave; in-wave DS order) ----
  float xq;
  {
    float acc = 0.f;
    const float *wq = p.Wq + lane * 32;
#pragma unroll
    for (int q = 0; q < 8; ++q) {
      const float4 w4 = *(const float4 *)(wq + q * 4);
      const float4 f4 = *(const float4 *)(fW + q * 4);
      acc = fmaf(w4.x, f4.x, fmaf(w4.y, f4.y, fmaf(w4.z, f4.z, fmaf(w4.w, f4.w, acc))));
    }
    const float s = p.gq[lane] * rsqrtf(p.vq[lane] + EPS);
    const float v = fmaf(acc, s, p.bq[lane] - p.mq[lane] * s);
    xq = v > 0.f ? v : 0.2f * v;
  }

  // ---- alpha = xq + sum_i w2[i]*pos1[i] ----
  float alpha = xq;
#pragma unroll
  for (int i = 0; i < 6; ++i) alpha = fmaf(w2[i], pos1[i], alpha);

  // ---- t[k] = sum_i w2[i]*x[i][k] via wave-uniform broadcast global loads ----
  const float *xbase = p.x + ((size_t)b * CIN * NPT + n) * KNN;  // + i*NPT*KNN + k
  float pre[32];
#pragma unroll
  for (int k = 0; k < 32; ++k) pre[k] = 0.f;
#pragma unroll
  for (int i = 0; i < 6; ++i) {
    const float *xr = xbase + (size_t)i * NPT * KNN;
    const float wv = w2[i];
#pragma unroll
    for (int q = 0; q < 8; ++q) {
      const float4 xx = *(const float4 *)(xr + q * 4);
      pre[q * 4 + 0] = fmaf(wv, xx.x, pre[q * 4 + 0]);
      pre[q * 4 + 1] = fmaf(wv, xx.y, pre[q * 4 + 1]);
      pre[q * 4 + 2] = fmaf(wv, xx.z, pre[q * 4 + 2]);
      pre[q * 4 + 3] = fmaf(wv, xx.w, pre[q * 4 + 3]);
    }
  }
  // beta[k] = (alpha - t[k]) * S2   (in place)
  const float aS = alpha * S2;
#pragma unroll
  for (int k = 0; k < 32; ++k) pre[k] = fmaf(-S2, pre[k], aS);

  // ---- stream y: stash bf16 frags in YB, finalize pre (log2 domain) ----
  const float *yrow = p.y + (((size_t)b * CF + lane) * NPT + n) * KNN;
#pragma unroll
  for (int q = 0; q < 8; ++q) {
    const float4 y4 = *(const float4 *)(yrow + q * 4);
    const float yv[4] = {y4.x, y4.y, y4.z, y4.w};
#pragma unroll
    for (int j = 0; j < 4; ++j) {
      const int k = q * 4 + j;
      YB[k * 64 + (lane ^ ((k & 7) << 3))] = bf16_rne(yv[j]);
      pre[k] = fmaf(-S2, yv[j], pre[k]);
    }
  }

  // ---- in-lane softmax (exp2 domain), UNNORMALIZED P -> PB ----
  float mx0 = pre[0], mx1 = pre[1], mx2 = pre[2], mx3 = pre[3];
#pragma unroll
  for (int k = 4; k < 32; k += 4) {
    mx0 = fmaxf(mx0, pre[k]);
    mx1 = fmaxf(mx1, pre[k + 1]);
    mx2 = fmaxf(mx2, pre[k + 2]);
    mx3 = fmaxf(mx3, pre[k + 3]);
  }
  const float mx = fmaxf(fmaxf(mx0, mx1), fmaxf(mx2, mx3));
  float s0 = 0.f, s1 = 0.f, s2 = 0.f, s3 = 0.f;
#pragma unroll
  for (int k = 0; k < 32; k += 4) {
    const float e0 = exp2f(pre[k + 0] - mx);
    const float e1 = exp2f(pre[k + 1] - mx);
    const float e2 = exp2f(pre[k + 2] - mx);
    const float e3 = exp2f(pre[k + 3] - mx);
    s0 += e0; s1 += e1; s2 += e2; s3 += e3;
    PB[(k + 0) * 64 + (lane ^ (((k + 0) & 7) << 3))] = bf16_rne(e0);
    PB[(k + 1) * 64 + (lane ^ (((k + 1) & 7) << 3))] = bf16_rne(e1);
    PB[(k + 2) * 64 + (lane ^ (((k + 2) & 7) << 3))] = bf16_rne(e2);
    PB[(k + 3) * 64 + (lane ^ (((k + 3) & 7) << 3))] = bf16_rne(e3);
  }
  const float inv = __builtin_amdgcn_rcpf((s0 + s1) + (s2 + s3));

  const int og = lane >> 4, kl = lane & 15;
  const int swz = (kl & 7) << 3;

  // ---- x values for the combine: direct global scalar loads ----
  float xv[6][2], ivx[6][2];
#pragma unroll
  for (int i = 0; i < 6; ++i)
#pragma unroll
    for (int nt = 0; nt < 2; ++nt) {
      xv[i][nt]  = xbase[(size_t)i * NPT * KNN + kl + nt * 16];
      ivx[i][nt] = inv * xv[i][nt];
    }

  // ---- P B-fragments (own writes; in-wave order) ----
  bf16x8 Ba[2][2];
#pragma unroll
  for (int ks = 0; ks < 2; ++ks)
#pragma unroll
    for (int nt = 0; nt < 2; ++nt)
      Ba[ks][nt] = *(const bf16x8 *)(PB + (kl + nt * 16) * 64 +
                                     ((ks * 32 + og * 8) ^ swz));

  // ---- GEMM1 per o-tile: acc init = sum(ba*xv) (off MFMA path), then
  //      out += g * ivx ; BN1+lrelu ; h over P ----
  const bf16x8 *WAv = (const bf16x8 *)p.WAf;
#pragma unroll
  for (int ot = 0; ot < 4; ++ot) {
    f32x4 o0 = {0.f, 0.f, 0.f, 0.f}, o1 = o0;
#pragma unroll
    for (int i = 0; i < 6; ++i) {
      const f32x4 ba4 = *(const f32x4 *)(p.baP + i * 64 + ot * 16 + og * 4);
#pragma unroll
      for (int r = 0; r < 4; ++r) {
        o0[r] = fmaf(ba4[r], xv[i][0], o0[r]);
        o1[r] = fmaf(ba4[r], xv[i][1], o1[r]);
      }
    }
#pragma unroll
    for (int i = 0; i < 6; ++i) {
      const bf16x8 A0 = WAv[((i * 4 + ot) * 2 + 0) * 64 + lane];
      const bf16x8 A1 = WAv[((i * 4 + ot) * 2 + 1) * 64 + lane];
      f32x4 g = {0.f, 0.f, 0.f, 0.f};
      g = __builtin_amdgcn_mfma_f32_16x16x32_bf16(A0, Ba[0][0], g, 0, 0, 0);
      g = __builtin_amdgcn_mfma_f32_16x16x32_bf16(A1, Ba[1][0], g, 0, 0, 0);
#pragma unroll
      for (int r = 0; r < 4; ++r) o0[r] = fmaf(g[r], ivx[i][0], o0[r]);
      g = (f32x4){0.f, 0.f, 0.f, 0.f};
      g = __builtin_amdgcn_mfma_f32_16x16x32_bf16(A0, Ba[0][1], g, 0, 0, 0);
      g = __builtin_amdgcn_mfma_f32_16x16x32_bf16(A1, Ba[1][1], g, 0, 0, 0);
#pragma unroll
      for (int r = 0; r < 4; ++r) o1[r] = fmaf(g[r], ivx[i][1], o1[r]);
    }
    const f32x4 s14 = *(const f32x4 *)(p.bnf + 0 * 64 + ot * 16 + og * 4);
    const f32x4 b14 = *(const f32x4 *)(p.bnf + 1 * 64 + ot * 16 + og * 4);
#pragma unroll
    for (int nt = 0; nt < 2; ++nt) {
      const f32x4 &oo = nt ? o1 : o0;
      float tt[4];
#pragma unroll
      for (int r = 0; r < 4; ++r) {
        const float v = fmaf(s14[r], oo[r], b14[r]);
        tt[r] = v > 0.f ? v : 0.2f * v;
      }
      const int idx = (kl + nt * 16) * 64 + ((ot * 16 + og * 4) ^ swz);
      *(uint2 *)(PB + idx) = make_uint2(pk2(tt[0], tt[1]), pk2(tt[2], tt[3]));
    }
  }

  // ---- GEMM2: out = lrelu( Wlin'@h + Wres'@y + blr ), split MFMA chains ----
  bf16x8 Bh[2][2], By[2][2];
#pragma unroll
  for (int ks = 0; ks < 2; ++ks)
#pragma unroll
    for (int nt = 0; nt < 2; ++nt) {
      const int off = (kl + nt * 16) * 64 + ((ks * 32 + og * 8) ^ swz);
      Bh[ks][nt] = *(const bf16x8 *)(PB + off);
      By[ks][nt] = *(const bf16x8 *)(YB + off);
    }

  const bf16x8 *WLv = (const bf16x8 *)p.WLf;
  const bf16x8 *WRv = (const bf16x8 *)p.WRf;
#pragma unroll
  for (int ot = 0; ot < 4; ++ot) {
    const bf16x8 L0 = WLv[(ot * 2 + 0) * 64 + lane];
    const bf16x8 L1 = WLv[(ot * 2 + 1) * 64 + lane];
    const bf16x8 R0 = WRv[(ot * 2 + 0) * 64 + lane];
    const bf16x8 R1 = WRv[(ot * 2 + 1) * 64 + lane];
    const f32x4 blr = *(const f32x4 *)(p.bnf + 2 * 64 + ot * 16 + og * 4);
#pragma unroll
    for (int nt = 0; nt < 2; ++nt) {
      f32x4 aL = {0.f, 0.f, 0.f, 0.f}, aR = aL;
      aL = __builtin_amdgcn_mfma_f32_16x16x32_bf16(L0, Bh[0][nt], aL, 0, 0, 0);
      aL = __builtin_amdgcn_mfma_f32_16x16x32_bf16(L1, Bh[1][nt], aL, 0, 0, 0);
      aR = __builtin_amdgcn_mfma_f32_16x16x32_bf16(R0, By[0][nt], aR, 0, 0, 0);
      aR = __builtin_amdgcn_mfma_f32_16x16x32_bf16(R1, By[1][nt], aR, 0, 0, 0);
      const int kcol = kl + nt * 16;
      float *ob = p.out + (((size_t)(b * CO + ot * 16 + og * 4)) * NPT + n) * KNN + kcol;
#pragma unroll
      for (int r = 0; r < 4; ++r) {
        const float v = (aL[r] + aR[r]) + blr[r];
        ob[(size_t)r * NPT * KNN] = v > 0.f ? v : 0.2f * v;
      }
    }
  }
}

extern "C" void kernel_launch(void *const *d_in, const int *in_sizes, int n_in,
                              void *d_out, int out_size, void *d_ws, size_t ws_size,
                              hipStream_t stream) {
  char *ws = (char *)d_ws;
  unsigned short *WAf = (unsigned short *)(ws + WS_WA);
  unsigned short *WLf = (unsigned short *)(ws + WS_WL);
  unsigned short *WRf = (unsigned short *)(ws + WS_WR);
  float *baP = (float *)(ws + WS_BA);
  float *bnf = (float *)(ws + WS_BNF);

  setup_kernel<<<dim3(96), dim3(256), 0, stream>>>(
      (const float *)d_in[7], (const float *)d_in[8], (const float *)d_in[9],
      (const float *)d_in[18], (const float *)d_in[19], (const float *)d_in[20], (const float *)d_in[21],
      (const float *)d_in[22], (const float *)d_in[23], (const float *)d_in[24], (const float *)d_in[25],
      (const float *)d_in[26], (const float *)d_in[27], (const float *)d_in[28], (const float *)d_in[29],
      (const float *)d_in[30], (const float *)d_in[31], (const float *)d_in[32], (const float *)d_in[33],
      WAf, WLf, WRf, baP, bnf);

  Params p;
  p.x      = (const float *)d_in[0];
  p.y      = (const float *)d_in[1];
  p.points = (const float *)d_in[2];
  p.feat   = (const float *)d_in[3];
  p.Wq     = (const float *)d_in[4];
  p.Wpos1  = (const float *)d_in[5];
  p.Wpos2  = (const float *)d_in[6];
  p.gq = (const float *)d_in[10]; p.bq = (const float *)d_in[11];
  p.mq = (const float *)d_in[12]; p.vq = (const float *)d_in[13];
  p.gp = (const float *)d_in[14]; p.bp = (const float *)d_in[15];
  p.mp = (const float *)d_in[16]; p.vp = (const float *)d_in[17];
  p.WAf = WAf; p.WLf = WLf; p.WRf = WRf;
  p.baP = baP; p.bnf = bnf;
  p.out = (float *)d_out;

  fused_pt_attn<<<dim3(NB * NPT / 4), dim3(256), 0, stream>>>(p);
}

// Round 11
// 76.300 us; speedup vs baseline: 1.1671x; 1.0419x over previous
//
#include <hip/hip_runtime.h>

// Problem constants (fixed by setup_inputs)
constexpr int NB  = 4;     // batch
constexpr int NPT = 2048;  // points (N)
constexpr int KNN = 32;    // neighbors (K)
constexpr int CIN = 6;     // in_channels
constexpr int CF  = 64;    // feat channels
constexpr int CO  = 64;    // out channels
constexpr float EPS = 1e-5f;

typedef short bf16x8 __attribute__((ext_vector_type(8)));   // 8 bf16 in 4 VGPRs
typedef float f32x4  __attribute__((ext_vector_type(4)));

// ---------------- workspace layout (bytes) ----------------
constexpr size_t WS_WA  = 0;       // WAf bf16[6*4*2*64*8] (sa-folded, row-permuted)
constexpr size_t WS_WL  = 49152;   // WLf bf16[4*2*64*8]  (sl-folded)
constexpr size_t WS_WR  = 57344;   // WRf bf16[4*2*64*8]  (sr-folded)
constexpr size_t WS_BA  = 65536;   // baP f32[6*64]
constexpr size_t WS_BNF = 67072;   // bnf f32[3*64]  (s1, b1, blr)

__device__ __host__ inline unsigned short bf16_rne(float f) {
  unsigned u = __builtin_bit_cast(unsigned, f);
  u += 0x7fffu + ((u >> 16) & 1u);
  return (unsigned short)(u >> 16);
}

__global__ void setup_kernel(const float *Wattn, const float *Wlin, const float *Wres,
                             const float *ga, const float *ba, const float *ma, const float *va,
                             const float *g1, const float *b1, const float *m1, const float *v1,
                             const float *gl, const float *bl, const float *ml, const float *vl,
                             const float *gr, const float *br, const float *mr, const float *vr,
                             unsigned short *WAf, unsigned short *WLf, unsigned short *WRf,
                             float *baP, float *bnf) {
  const int t = blockIdx.x * blockDim.x + threadIdx.x;
  const int stride = gridDim.x * blockDim.x;
  for (int e = t; e < 6 * 4 * 2 * 64 * 8; e += stride) {
    const int j = e & 7, l = (e >> 3) & 63, ks = (e >> 9) & 1, ot = (e >> 10) & 3, i = e >> 12;
    const int m = l & 15, cg = l >> 4;
    const int cc = ks * 32 + cg * 8 + j;
    const int row = (ot * 16 + m) * CIN + i;
    const float sa = ga[row] * rsqrtf(va[row] + EPS);
    WAf[e] = bf16_rne(Wattn[row * CF + cc] * sa);
  }
  for (int e = t; e < 4 * 2 * 64 * 8; e += stride) {
    const int j = e & 7, l = (e >> 3) & 63, ks = (e >> 9) & 1, ot = e >> 10;
    const int m = l & 15;
    const int cc = ks * 32 + (l >> 4) * 8 + j;
    const int row = ot * 16 + m;
    const float sl = gl[row] * rsqrtf(vl[row] + EPS);
    const float sr = gr[row] * rsqrtf(vr[row] + EPS);
    WLf[e] = bf16_rne(Wlin[row * CF + cc] * sl);
    WRf[e] = bf16_rne(Wres[row * CF + cc] * sr);
  }
  for (int e = t; e < 384; e += stride) {
    const int i = e >> 6, o = e & 63;
    const int j0 = o * CIN + i;
    const float sa = ga[j0] * rsqrtf(va[j0] + EPS);
    baP[e] = ba[j0] - ma[j0] * sa;
  }
  for (int e = t; e < 64; e += stride) {
    const float s1v = g1[e] * rsqrtf(v1[e] + EPS);
    bnf[e]      = s1v;
    bnf[64 + e] = b1[e] - m1[e] * s1v;
    const float slv = gl[e] * rsqrtf(vl[e] + EPS);
    const float srv = gr[e] * rsqrtf(vr[e] + EPS);
    bnf[128 + e] = (bl[e] - ml[e] * slv) + (br[e] - mr[e] * srv);
  }
}

struct Params {
  const float *x, *y, *points, *feat;
  const float *Wq, *Wpos1, *Wpos2;
  const float *gq, *bq, *mq, *vq;
  const float *gp, *bp, *mp, *vp;
  const unsigned short *WAf, *WLf, *WRf;
  const float *baP, *bnf;
  float *out;
};

// Block = 4 waves = 2 groups x 2 waves; block handles 4 points.
// Stage: wave w stages point (bid*4+w) into its own LDS slot (R3 verbatim,
// but stores RAW x and folds alpha = xq + sum w2*pos1).
// GEMM: within each group, wave j computes o-tiles {2j,2j+1} for BOTH of the
// group's points -> per-wave weight traffic 64KB -> 32KB for 2 points (4x/pt).
// Barriers: stage -> (bar) frag hoist -> (bar) GEMM1+h -> (bar) GEMM2.
__global__ __launch_bounds__(256) void fused_pt_attn(Params p) {
  const int tid  = threadIdx.x;
  const int lane = tid & 63;
  const int wid  = tid >> 6;
  // XCD-aware swizzle: 2048 blocks, 8 XCDs -> each XCD gets a contiguous range.
  const int bid  = ((blockIdx.x & 7) << 8) + (blockIdx.x >> 3);
  const int b    = bid >> 9;                 // 4 points per block, same batch
  const int n    = (bid * 4 + wid) & (NPT - 1);

  __shared__ unsigned short s_Y[4][2048];    // y bf16 frags per slot
  __shared__ unsigned short s_P[4][2048];    // P (softmax) -> h per slot
  __shared__ float s_x[4][192];              // raw x[i][k] per slot
  __shared__ float s_f[4][32];               // feat per slot
  unsigned short *YB = s_Y[wid];
  unsigned short *PB = s_P[wid];
  float *xW = s_x[wid];
  float *fW = s_f[wid];

  // ================= stage own point =================
  {
    float ftv = 0.f, ptv = 0.f;
    if (lane < 32) ftv = p.feat[((size_t)b * 32 + lane) * NPT + n];
    if (lane < 3)  ptv = p.points[((size_t)b * 3 + lane) * NPT + n];
    const int xi = lane >> 3, xk = (lane & 7) * 4;
    float4 x4 = make_float4(0.f, 0.f, 0.f, 0.f);
    if (lane < 48)
      x4 = *(const float4 *)(p.x + (((size_t)b * CIN + xi) * NPT + n) * KNN + xk);
    const float *w2p = p.Wpos2 + lane * 6;   // Wpos2[c][i]
    const float2 w2a = *(const float2 *)(w2p);
    const float2 w2b = *(const float2 *)(w2p + 2);
    const float2 w2c = *(const float2 *)(w2p + 4);
    const float w2[6] = {w2a.x, w2a.y, w2b.x, w2b.y, w2c.x, w2c.y};

    if (lane < 32) fW[lane] = ftv;
    if (lane < 48) *(float4 *)(xW + xi * 32 + xk) = x4;

    // pos1 (all lanes)
    const float pt0 = __shfl(ptv, 0), pt1 = __shfl(ptv, 1), pt2 = __shfl(ptv, 2);
    float pos1[6];
#pragma unroll
    for (int i = 0; i < 6; ++i) {
      const float a = p.Wpos1[i * 3 + 0] * pt0 + p.Wpos1[i * 3 + 1] * pt1 +
                      p.Wpos1[i * 3 + 2] * pt2;
      const float s = p.gp[i] * rsqrtf(p.vp[i] + EPS);
      const float v = fmaf(a, s, p.bp[i] - p.mp[i] * s);
      pos1[i] = v > 0.f ? v : 0.2f * v;
    }

    // x_q[lane]
    float xq;
    {
      float acc = 0.f;
      const float *wq = p.Wq + lane * 32;
#pragma unroll
      for (int q = 0; q < 8; ++q) {
        const float4 w4 = *(const float4 *)(wq + q * 4);
        const float4 f4 = *(const float4 *)(fW + q * 4);
        acc = fmaf(w4.x, f4.x, fmaf(w4.y, f4.y, fmaf(w4.z, f4.z, fmaf(w4.w, f4.w, acc))));
      }
      const float s = p.gq[lane] * rsqrtf(p.vq[lane] + EPS);
      const float v = fmaf(acc, s, p.bq[lane] - p.mq[lane] * s);
      xq = v > 0.f ? v : 0.2f * v;
    }

    // alpha = xq + sum_i w2[i]*pos1[i]
    float alpha = xq;
#pragma unroll
    for (int i = 0; i < 6; ++i) alpha = fmaf(w2[i], pos1[i], alpha);

    // t[k] = sum_i w2[i]*x[i][k]  (broadcast b128 reads of own slot)
    float pre[32];
#pragma unroll
    for (int k = 0; k < 32; ++k) pre[k] = 0.f;
#pragma unroll
    for (int i = 0; i < 6; ++i) {
      const float wv = w2[i];
#pragma unroll
      for (int q = 0; q < 8; ++q) {
        const float4 d4 = *(const float4 *)(xW + i * 32 + q * 4);
        pre[q * 4 + 0] = fmaf(wv, d4.x, pre[q * 4 + 0]);
        pre[q * 4 + 1] = fmaf(wv, d4.y, pre[q * 4 + 1]);
        pre[q * 4 + 2] = fmaf(wv, d4.z, pre[q * 4 + 2]);
        pre[q * 4 + 3] = fmaf(wv, d4.w, pre[q * 4 + 3]);
      }
    }

    // stream y: stash bf16 frags, finalize pre = (alpha - t - y)/8
    const float *yrow = p.y + (((size_t)b * CF + lane) * NPT + n) * KNN;
#pragma unroll
    for (int q = 0; q < 8; ++q) {
      const float4 y4 = *(const float4 *)(yrow + q * 4);
      const float yv[4] = {y4.x, y4.y, y4.z, y4.w};
#pragma unroll
      for (int j = 0; j < 4; ++j) {
        const int k = q * 4 + j;
        YB[k * 64 + (lane ^ ((k & 7) << 3))] = bf16_rne(yv[j]);
        pre[k] = (alpha - pre[k] - yv[j]) * 0.125f;
      }
    }

    // in-lane softmax (normalized), write P
    float mx = pre[0];
#pragma unroll
    for (int k = 1; k < 32; ++k) mx = fmaxf(mx, pre[k]);
    float sum = 0.f;
#pragma unroll
    for (int k = 0; k < 32; ++k) { pre[k] = __expf(pre[k] - mx); sum += pre[k]; }
    const float inv = 1.f / sum;
#pragma unroll
    for (int k = 0; k < 32; ++k)
      PB[k * 64 + (lane ^ ((k & 7) << 3))] = bf16_rne(pre[k] * inv);
  }
  __syncthreads();  // bar1: all 4 points staged

  // ================= GEMM phase: group shares points, splits o-tiles ======
  const int s0  = wid & 2;          // group's slot pair: s0, s0+1
  const int s1  = s0 + 1;
  const int otb = (wid & 1) * 2;    // this wave's o-tile base (0 or 2)
  const int n0  = (bid * 4 + s0) & (NPT - 1);
  const int og = lane >> 4, kl = lane & 15;
  const int swz = (kl & 7) << 3;

  // hoist P fragments of both points + x-combine values
  bf16x8 Ba0[2][2], Ba1[2][2];
#pragma unroll
  for (int ks = 0; ks < 2; ++ks)
#pragma unroll
    for (int nt = 0; nt < 2; ++nt) {
      const int off = (kl + nt * 16) * 64 + ((ks * 32 + og * 8) ^ swz);
      Ba0[ks][nt] = *(const bf16x8 *)(s_P[s0] + off);
      Ba1[ks][nt] = *(const bf16x8 *)(s_P[s1] + off);
    }
  float xv0[6][2], xv1[6][2];
#pragma unroll
  for (int i = 0; i < 6; ++i)
#pragma unroll
    for (int nt = 0; nt < 2; ++nt) {
      xv0[i][nt] = s_x[s0][i * 32 + kl + nt * 16];
      xv1[i][nt] = s_x[s1][i * 32 + kl + nt * 16];
    }
  __syncthreads();  // bar2: all P/x reads hoisted -> safe to overwrite P with h

  // GEMM1: this wave's 2 o-tiles for both points; h written over P
  const bf16x8 *WAv = (const bf16x8 *)p.WAf;
#pragma unroll
  for (int ot2 = 0; ot2 < 2; ++ot2) {
    const int ot = otb + ot2;
    f32x4 o00 = {0.f, 0.f, 0.f, 0.f}, o01 = o00, o10 = o00, o11 = o00;  // [pt][nt]
#pragma unroll
    for (int i = 0; i < 6; ++i) {
      const bf16x8 A0 = WAv[((i * 4 + ot) * 2 + 0) * 64 + lane];
      const bf16x8 A1 = WAv[((i * 4 + ot) * 2 + 1) * 64 + lane];
      const f32x4 ba4 = *(const f32x4 *)(p.baP + i * 64 + ot * 16 + og * 4);
      f32x4 g;
      g = (f32x4){0.f, 0.f, 0.f, 0.f};
      g = __builtin_amdgcn_mfma_f32_16x16x32_bf16(A0, Ba0[0][0], g, 0, 0, 0);
      g = __builtin_amdgcn_mfma_f32_16x16x32_bf16(A1, Ba0[1][0], g, 0, 0, 0);
#pragma unroll
      for (int r = 0; r < 4; ++r) o00[r] = fmaf(g[r] + ba4[r], xv0[i][0], o00[r]);
      g = (f32x4){0.f, 0.f, 0.f, 0.f};
      g = __builtin_amdgcn_mfma_f32_16x16x32_bf16(A0, Ba0[0][1], g, 0, 0, 0);
      g = __builtin_amdgcn_mfma_f32_16x16x32_bf16(A1, Ba0[1][1], g, 0, 0, 0);
#pragma unroll
      for (int r = 0; r < 4; ++r) o01[r] = fmaf(g[r] + ba4[r], xv0[i][1], o01[r]);
      g = (f32x4){0.f, 0.f, 0.f, 0.f};
      g = __builtin_amdgcn_mfma_f32_16x16x32_bf16(A0, Ba1[0][0], g, 0, 0, 0);
      g = __builtin_amdgcn_mfma_f32_16x16x32_bf16(A1, Ba1[1][0], g, 0, 0, 0);
#pragma unroll
      for (int r = 0; r < 4; ++r) o10[r] = fmaf(g[r] + ba4[r], xv1[i][0], o10[r]);
      g = (f32x4){0.f, 0.f, 0.f, 0.f};
      g = __builtin_amdgcn_mfma_f32_16x16x32_bf16(A0, Ba1[0][1], g, 0, 0, 0);
      g = __builtin_amdgcn_mfma_f32_16x16x32_bf16(A1, Ba1[1][1], g, 0, 0, 0);
#pragma unroll
      for (int r = 0; r < 4; ++r) o11[r] = fmaf(g[r] + ba4[r], xv1[i][1], o11[r]);
    }
    const f32x4 s14 = *(const f32x4 *)(p.bnf + 0 * 64 + ot * 16 + og * 4);
    const f32x4 b14 = *(const f32x4 *)(p.bnf + 1 * 64 + ot * 16 + og * 4);
#pragma unroll
    for (int nt = 0; nt < 2; ++nt) {
      const int idx = (kl + nt * 16) * 64 + ((ot * 16 + og * 4) ^ swz);
      const f32x4 &q0 = nt ? o01 : o00;
      const f32x4 &q1 = nt ? o11 : o10;
      unsigned h0[4], h1[4];
#pragma unroll
      for (int r = 0; r < 4; ++r) {
        const float t0 = fmaf(s14[r], q0[r], b14[r]);
        const float t1 = fmaf(s14[r], q1[r], b14[r]);
        h0[r] = bf16_rne(t0 > 0.f ? t0 : 0.2f * t0);
        h1[r] = bf16_rne(t1 > 0.f ? t1 : 0.2f * t1);
      }
      *(uint2 *)(s_P[s0] + idx) = make_uint2(h0[0] | (h0[1] << 16), h0[2] | (h0[3] << 16));
      *(uint2 *)(s_P[s1] + idx) = make_uint2(h1[0] | (h1[1] << 16), h1[2] | (h1[3] << 16));
    }
  }
  __syncthreads();  // bar3: h complete for all channels

  // GEMM2: this wave's 2 o-tiles for both points
  bf16x8 Bh0[2][2], Bh1[2][2], By0[2][2], By1[2][2];
#pragma unroll
  for (int ks = 0; ks < 2; ++ks)
#pragma unroll
    for (int nt = 0; nt < 2; ++nt) {
      const int off = (kl + nt * 16) * 64 + ((ks * 32 + og * 8) ^ swz);
      Bh0[ks][nt] = *(const bf16x8 *)(s_P[s0] + off);
      Bh1[ks][nt] = *(const bf16x8 *)(s_P[s1] + off);
      By0[ks][nt] = *(const bf16x8 *)(s_Y[s0] + off);
      By1[ks][nt] = *(const bf16x8 *)(s_Y[s1] + off);
    }

  const bf16x8 *WLv = (const bf16x8 *)p.WLf;
  const bf16x8 *WRv = (const bf16x8 *)p.WRf;
#pragma unroll
  for (int ot2 = 0; ot2 < 2; ++ot2) {
    const int ot = otb + ot2;
    const bf16x8 L0 = WLv[(ot * 2 + 0) * 64 + lane];
    const bf16x8 L1 = WLv[(ot * 2 + 1) * 64 + lane];
    const bf16x8 R0 = WRv[(ot * 2 + 0) * 64 + lane];
    const bf16x8 R1 = WRv[(ot * 2 + 1) * 64 + lane];
    const f32x4 blr = *(const f32x4 *)(p.bnf + 2 * 64 + ot * 16 + og * 4);
#pragma unroll
    for (int nt = 0; nt < 2; ++nt) {
      f32x4 a0 = {0.f, 0.f, 0.f, 0.f}, a1 = a0;
      a0 = __builtin_amdgcn_mfma_f32_16x16x32_bf16(L0, Bh0[0][nt], a0, 0, 0, 0);
      a0 = __builtin_amdgcn_mfma_f32_16x16x32_bf16(L1, Bh0[1][nt], a0, 0, 0, 0);
      a0 = __builtin_amdgcn_mfma_f32_16x16x32_bf16(R0, By0[0][nt], a0, 0, 0, 0);
      a0 = __builtin_amdgcn_mfma_f32_16x16x32_bf16(R1, By0[1][nt], a0, 0, 0, 0);
      a1 = __builtin_amdgcn_mfma_f32_16x16x32_bf16(L0, Bh1[0][nt], a1, 0, 0, 0);
      a1 = __builtin_amdgcn_mfma_f32_16x16x32_bf16(L1, Bh1[1][nt], a1, 0, 0, 0);
      a1 = __builtin_amdgcn_mfma_f32_16x16x32_bf16(R0, By1[0][nt], a1, 0, 0, 0);
      a1 = __builtin_amdgcn_mfma_f32_16x16x32_bf16(R1, By1[1][nt], a1, 0, 0, 0);
      const int kcol = kl + nt * 16;
      float *ob = p.out + (((size_t)(b * CO + ot * 16 + og * 4)) * NPT + n0) * KNN + kcol;
#pragma unroll
      for (int r = 0; r < 4; ++r) {
        const float v0 = a0[r] + blr[r];
        const float v1 = a1[r] + blr[r];
        ob[(size_t)r * NPT * KNN]       = v0 > 0.f ? v0 : 0.2f * v0;
        ob[(size_t)r * NPT * KNN + KNN] = v1 > 0.f ? v1 : 0.2f * v1;
      }
    }
  }
}

extern "C" void kernel_launch(void *const *d_in, const int *in_sizes, int n_in,
                              void *d_out, int out_size, void *d_ws, size_t ws_size,
                              hipStream_t stream) {
  char *ws = (char *)d_ws;
  unsigned short *WAf = (unsigned short *)(ws + WS_WA);
  unsigned short *WLf = (unsigned short *)(ws + WS_WL);
  unsigned short *WRf = (unsigned short *)(ws + WS_WR);
  float *baP = (float *)(ws + WS_BA);
  float *bnf = (float *)(ws + WS_BNF);

  setup_kernel<<<dim3(96), dim3(256), 0, stream>>>(
      (const float *)d_in[7], (const float *)d_in[8], (const float *)d_in[9],
      (const float *)d_in[18], (const float *)d_in[19], (const float *)d_in[20], (const float *)d_in[21],
      (const float *)d_in[22], (const float *)d_in[23], (const float *)d_in[24], (const float *)d_in[25],
      (const float *)d_in[26], (const float *)d_in[27], (const float *)d_in[28], (const float *)d_in[29],
      (const float *)d_in[30], (const float *)d_in[31], (const float *)d_in[32], (const float *)d_in[33],
      WAf, WLf, WRf, baP, bnf);

  Params p;
  p.x      = (const float *)d_in[0];
  p.y      = (const float *)d_in[1];
  p.points = (const float *)d_in[2];
  p.feat   = (const float *)d_in[3];
  p.Wq     = (const float *)d_in[4];
  p.Wpos1  = (const float *)d_in[5];
  p.Wpos2  = (const float *)d_in[6];
  p.gq = (const float *)d_in[10]; p.bq = (const float *)d_in[11];
  p.mq = (const float *)d_in[12]; p.vq = (const float *)d_in[13];
  p.gp = (const float *)d_in[14]; p.bp = (const float *)d_in[15];
  p.mp = (const float *)d_in[16]; p.vp = (const float *)d_in[17];
  p.WAf = WAf; p.WLf = WLf; p.WRf = WRf;
  p.baP = baP; p.bnf = bnf;
  p.out = (float *)d_out;

  fused_pt_attn<<<dim3(NB * NPT / 4), dim3(256), 0, stream>>>(p);
}